// Round 10
// baseline (201.590 us; speedup 1.0000x reference)
//
#include <hip/hip_runtime.h>
#include <stdint.h>

#define DIM 768
#define HEADS 12
#define HD 64
#define BATCH 4
#define SEQ 1024
#define NTOK (BATCH*SEQ)   // 4096
#define QKVW (3*DIM)       // 2304
#define QKW (2*DIM)        // 1536
#define EPS 1e-5f

typedef __attribute__((ext_vector_type(8))) short short8;   // 8 bf16 (4 VGPRs)
typedef __attribute__((ext_vector_type(4))) float f32x4;    // MFMA C/D

// ---- fp32 <-> bf16 ----
__device__ __forceinline__ unsigned short f2bf(float f) {
    union { float f; unsigned u; } v; v.f = f;
    unsigned r = v.u + 0x7fffu + ((v.u >> 16) & 1u);   // RNE
    return (unsigned short)(r >> 16);
}
__device__ __forceinline__ float b2f(unsigned short s) {
    union { unsigned u; float f; } v; v.u = (unsigned)s << 16; return v.f;
}

// ==================== combined conversions (1 launch) ====================
#define CVT_X_BLOCKS (NTOK*DIM/4096)            // 768 (4 float4 per thread)
#define CVT_WQ_TILES ((QKVW/32)*(DIM/32))       // 1728
#define CVT_WP_TILES ((DIM/32)*(DIM/32))        // 576
__global__ __launch_bounds__(256) void cvt_all_kernel(
    const float* __restrict__ x,
    const float* __restrict__ Wq0, const float* __restrict__ Wq1,
    const float* __restrict__ Wp0, const float* __restrict__ Wp1,
    unsigned short* __restrict__ xb,
    unsigned short* __restrict__ WqT0, unsigned short* __restrict__ WqT1,
    unsigned short* __restrict__ WpT0, unsigned short* __restrict__ WpT1)
{
    const int bid = blockIdx.x, tid = threadIdx.x;
    if (bid < CVT_X_BLOCKS) {
        const int base = bid * 1024 + tid;
#pragma unroll
        for (int u = 0; u < 4; ++u) {
            const float4 v = ((const float4*)x)[base + u * 256];
            ushort4 o4;
            o4.x = f2bf(v.x); o4.y = f2bf(v.y); o4.z = f2bf(v.z); o4.w = f2bf(v.w);
            ((ushort4*)xb)[base + u * 256] = o4;
        }
        return;
    }
    __shared__ float t[32][33];
    const float* W; unsigned short* WT; int N, K, tile;
    int w = bid - CVT_X_BLOCKS;
    if (w < 2 * CVT_WQ_TILES) {
        const int z = w / CVT_WQ_TILES; tile = w % CVT_WQ_TILES;
        W = z ? Wq1 : Wq0; WT = z ? WqT1 : WqT0; N = QKVW; K = DIM;
    } else {
        w -= 2 * CVT_WQ_TILES;
        const int z = w / CVT_WP_TILES; tile = w % CVT_WP_TILES;
        W = z ? Wp1 : Wp0; WT = z ? WpT1 : WpT0; N = DIM; K = DIM;
    }
    const int ntiles = N / 32;
    const int n0 = (tile % ntiles) * 32, k0 = (tile / ntiles) * 32;
    const int c = tid & 31, rr = tid >> 5;
#pragma unroll
    for (int i = 0; i < 4; ++i)
        t[rr + 8 * i][c] = W[(size_t)(k0 + rr + 8 * i) * N + n0 + c];
    __syncthreads();
#pragma unroll
    for (int i = 0; i < 4; ++i)
        WT[(size_t)(n0 + rr + 8 * i) * K + k0 + c] = f2bf(t[c][rr + 8 * i]);
}

// ==================== fused QKV GEMM, reg-staged padded-LDS dbuf ====================
// 1D grid (1152): id%8 -> XCD tile (gx,gy,gz): per-XCD 9x16 block tile (B-panels
// L2-resident, A split 2x). Staging: regs -> ds_write_b128 into pitch-36-word
// rows (bank stride 4 -> 2-way = free). One barrier per K-iter.
#define QP 36   // row pitch in shorts (32 data + 4 pad)
__global__ __launch_bounds__(256) void gemm_qkv_kernel(
    const unsigned short* __restrict__ A,     // xb [4096][768]
    const unsigned short* __restrict__ BT0, const unsigned short* __restrict__ BT1,
    const float* __restrict__ bias0, const float* __restrict__ bias1,
    unsigned short* __restrict__ QK0, unsigned short* __restrict__ QK1,
    unsigned short* __restrict__ VT0, unsigned short* __restrict__ VT1)
{
    // decode swizzled block id
    const int gid = blockIdx.x;
    const int g = gid & 7, t = gid >> 3;          // t: 0..143
    const int bx = (g & 1) * 9 + t % 9;           // 0..17
    const int by = ((g >> 1) & 1) * 16 + t / 9;   // 0..31
    const int z = g >> 2;
    const unsigned short* __restrict__ BT = z ? BT1 : BT0;
    const float* __restrict__ bias = z ? bias1 : bias0;
    unsigned short* __restrict__ QK = z ? QK1 : QK0;
    unsigned short* __restrict__ VT = z ? VT1 : VT0;
    const int K = DIM;
    const int m0 = by * 128, n0 = bx * 128;

    // sh: staging buf p at [p*9216] (A 128*36=4608, B 4608 shorts);
    // epilogue overlays sh as C tile [128][136] (17408 shorts)
    __shared__ __align__(16) unsigned short sh[18432];   // 36.9 KB
    const int tid = threadIdx.x, lane = tid & 63, wv = tid >> 6;
    const int wr = wv >> 1, wc = wv & 1;
    const int fm = lane & 15, fk = (lane >> 4) * 8;
    const int sr = wv * 32 + (lane >> 2);     // staging row (this + +16)
    const int ck = (lane & 3) * 8;            // staging chunk offset (shorts)

    const unsigned short* Ag0 = A  + (size_t)(m0 + sr)      * K + ck;
    const unsigned short* Ag1 = A  + (size_t)(m0 + sr + 16) * K + ck;
    const unsigned short* Bg0 = BT + (size_t)(n0 + sr)      * K + ck;
    const unsigned short* Bg1 = BT + (size_t)(n0 + sr + 16) * K + ck;

    f32x4 acc[4][4];
#pragma unroll
    for (int i = 0; i < 4; ++i)
#pragma unroll
        for (int j = 0; j < 4; ++j) acc[i][j] = f32x4{0.f, 0.f, 0.f, 0.f};

    // prologue: tile 0 in regs
    uint4 a0 = *(const uint4*)Ag0, a1 = *(const uint4*)Ag1;
    uint4 b0 = *(const uint4*)Bg0, b1 = *(const uint4*)Bg1;

    const int NK = K / 32;   // 24
    for (int kt = 0; kt < NK; ++kt) {
        const int pb = (kt & 1) * 9216;
        *(uint4*)&sh[pb + sr * QP + ck]               = a0;
        *(uint4*)&sh[pb + (sr + 16) * QP + ck]        = a1;
        *(uint4*)&sh[pb + 4608 + sr * QP + ck]        = b0;
        *(uint4*)&sh[pb + 4608 + (sr + 16) * QP + ck] = b1;
        if (kt + 1 < NK) {
            const int off = (kt + 1) * 32;
            a0 = *(const uint4*)(Ag0 + off); a1 = *(const uint4*)(Ag1 + off);
            b0 = *(const uint4*)(Bg0 + off); b1 = *(const uint4*)(Bg1 + off);
        }
        __syncthreads();
        short8 af[4], bf[4];
#pragma unroll
        for (int i = 0; i < 4; ++i)
            af[i] = *(const short8*)&sh[pb + (wr * 64 + i * 16 + fm) * QP + fk];
#pragma unroll
        for (int j = 0; j < 4; ++j)
            bf[j] = *(const short8*)&sh[pb + 4608 + (wc * 64 + j * 16 + fm) * QP + fk];
#pragma unroll
        for (int i = 0; i < 4; ++i)
#pragma unroll
            for (int j = 0; j < 4; ++j)
                acc[i][j] = __builtin_amdgcn_mfma_f32_16x16x32_bf16(af[i], bf[j], acc[i][j], 0, 0, 0);
        __syncthreads();   // all waves done with buf before overwrite / epilogue
    }

    const int rbase = (lane >> 4) * 4;
    const int rowg = tid >> 4, lseg = tid & 15;
    if (n0 < QKW) {
        const float qsc = (n0 < DIM) ? 0.125f : 1.0f;   // fold 1/sqrt(64) into Q
#pragma unroll
        for (int i = 0; i < 4; ++i) {
            const int ml = wr * 64 + i * 16 + rbase;
#pragma unroll
            for (int j = 0; j < 4; ++j) {
                const int nl = wc * 64 + j * 16 + fm;
                const float bs = bias[n0 + nl];
#pragma unroll
                for (int r = 0; r < 4; ++r)
                    sh[(ml + r) * 136 + nl] = f2bf((acc[i][j][r] + bs) * qsc);
            }
        }
        __syncthreads();
#pragma unroll
        for (int pp = 0; pp < 8; ++pp) {
            const int row = pp * 16 + rowg;
            const uint4 v = *(const uint4*)&sh[row * 136 + lseg * 8];
            *(uint4*)(QK + (size_t)(m0 + row) * QKW + n0 + lseg * 8) = v;
        }
    } else {
        const int b = m0 >> 10, t0 = m0 & 1023;
#pragma unroll
        for (int i = 0; i < 4; ++i) {
            const int tl = wr * 64 + i * 16 + rbase;
#pragma unroll
            for (int j = 0; j < 4; ++j) {
                const int nl = wc * 64 + j * 16 + fm;
                const float bs = bias[n0 + nl];
                const unsigned p0 = f2bf(acc[i][j][0] + bs);
                const unsigned p1 = f2bf(acc[i][j][1] + bs);
                const unsigned p2 = f2bf(acc[i][j][2] + bs);
                const unsigned p3 = f2bf(acc[i][j][3] + bs);
                uint2 u; u.x = p0 | (p1 << 16); u.y = p2 | (p3 << 16);
                *(uint2*)(&sh[nl * 136 + tl]) = u;
            }
        }
        __syncthreads();
#pragma unroll
        for (int pp = 0; pp < 8; ++pp) {
            const int nl = pp * 16 + rowg;
            const int nh = (n0 - QKW) + nl;
            const uint4 v = *(const uint4*)&sh[nl * 136 + lseg * 8];
            *(uint4*)(VT + ((size_t)((b * HEADS + (nh >> 6)) * HD + (nh & 63))) * SEQ
                      + t0 + lseg * 8) = v;
        }
    }
}

// ==================== proj GEMM, reg-staged padded-LDS dbuf ====================
// grid (6, 64, 2): 64x128 tile, K=768 per branch -> 768 blocks (3/CU).
// z=0: Y0 = acc + x + b0 + b1 (fp32); z=1: Y1 = acc (bf16). ln sums Y0+Y1.
__global__ __launch_bounds__(256) void gemm_proj_kernel(
    const unsigned short* __restrict__ A0, const unsigned short* __restrict__ BT0,
    const unsigned short* __restrict__ A1, const unsigned short* __restrict__ BT1,
    const float* __restrict__ b0, const float* __restrict__ b1,
    const float* __restrict__ xres, float* __restrict__ Y0,
    unsigned short* __restrict__ Y1)
{
    const int z = blockIdx.z;
    const unsigned short* __restrict__ A  = z ? A1 : A0;
    const unsigned short* __restrict__ BT = z ? BT1 : BT0;
    __shared__ __align__(16) unsigned short shA[2][64 * QP];    // 2 x 4.6 KB
    __shared__ __align__(16) unsigned short shB[2][128 * QP];   // 2 x 9.2 KB
    const int tid = threadIdx.x, lane = tid & 63, wv = tid >> 6;
    const int m0 = blockIdx.y * 64, n0 = blockIdx.x * 128;
    const int fm = lane & 15, fg = lane >> 4, fk = (lane >> 4) * 8;
    const int srw = lane >> 2, ck = (lane & 3) * 8;
    const int K = DIM;

    const unsigned short* Ag  = A  + (size_t)(m0 + wv * 16 + srw) * K + ck;
    const unsigned short* Bg0 = BT + (size_t)(n0 + wv * 32 + srw) * K + ck;
    const unsigned short* Bg1 = BT + (size_t)(n0 + wv * 32 + 16 + srw) * K + ck;
    const int sa = (wv * 16 + srw) * QP + ck;
    const int sb0 = (wv * 32 + srw) * QP + ck;
    const int sb1 = (wv * 32 + 16 + srw) * QP + ck;

    f32x4 acc[4][2];
#pragma unroll
    for (int i = 0; i < 4; ++i)
#pragma unroll
        for (int j = 0; j < 2; ++j) acc[i][j] = f32x4{0.f, 0.f, 0.f, 0.f};

    uint4 ar = *(const uint4*)Ag;
    uint4 br0 = *(const uint4*)Bg0, br1 = *(const uint4*)Bg1;

    const int NK = K / 32;   // 24
    for (int kt = 0; kt < NK; ++kt) {
        const int p = kt & 1;
        *(uint4*)&shA[p][sa]  = ar;
        *(uint4*)&shB[p][sb0] = br0;
        *(uint4*)&shB[p][sb1] = br1;
        if (kt + 1 < NK) {
            const int off = (kt + 1) * 32;
            ar  = *(const uint4*)(Ag + off);
            br0 = *(const uint4*)(Bg0 + off);
            br1 = *(const uint4*)(Bg1 + off);
        }
        __syncthreads();
        short8 af[4], bf[2];
#pragma unroll
        for (int i = 0; i < 4; ++i)
            af[i] = *(const short8*)&shA[p][(i * 16 + fm) * QP + fk];
#pragma unroll
        for (int j = 0; j < 2; ++j)
            bf[j] = *(const short8*)&shB[p][(wv * 32 + j * 16 + fm) * QP + fk];
#pragma unroll
        for (int i = 0; i < 4; ++i)
#pragma unroll
            for (int j = 0; j < 2; ++j)
                acc[i][j] = __builtin_amdgcn_mfma_f32_16x16x32_bf16(af[i], bf[j], acc[i][j], 0, 0, 0);
        __syncthreads();
    }
    // epilogue: C row = fg*4+r (m-dir), col = fm (n-dir)
#pragma unroll
    for (int i = 0; i < 4; ++i) {
        const int m = m0 + i * 16 + fg * 4;
#pragma unroll
        for (int j = 0; j < 2; ++j) {
            const int n = n0 + wv * 32 + j * 16 + fm;
            if (z == 0) {
                const float bs = b0[n] + b1[n];
#pragma unroll
                for (int r = 0; r < 4; ++r) {
                    const size_t idx = (size_t)(m + r) * DIM + n;
                    Y0[idx] = acc[i][j][r] + xres[idx] + bs;
                }
            } else {
#pragma unroll
                for (int r = 0; r < 4; ++r)
                    Y1[(size_t)(m + r) * DIM + n] = f2bf(acc[i][j][r]);
            }
        }
    }
}

// ==================== fused MFMA flash attention, dbuf LDS K/V, 1 barrier/iter ====================
#define KP 72    // LDS pitch in shorts (144B rows)
__global__ __launch_bounds__(256, 3) void attn_fused_kernel(
    const unsigned short* __restrict__ qk_c, const unsigned short* __restrict__ vT_c,
    const unsigned short* __restrict__ qk_ac, const unsigned short* __restrict__ vT_ac,
    unsigned short* __restrict__ o_c, unsigned short* __restrict__ o_ac)
{
    __shared__ __align__(16) unsigned short Kls[2][64 * KP];   // 18 KB
    __shared__ __align__(16) unsigned short Vls[2][64 * KP];   // 18 KB ([d][kc])
    __shared__ __align__(16) unsigned short Ps[4][16 * KP];    // 9 KB, wave-private
    const int tid = threadIdx.x, lane = tid & 63, w = tid >> 6;
    const int fm = lane & 15, fg = lane >> 4;
    const int bh = blockIdx.x, qt = blockIdx.y;
    const int b = bh / HEADS, h = bh % HEADS;
    unsigned short* Psw = &Ps[w][0];
    const int srow = tid >> 3, sseg = (tid & 7) * 8;

    for (int br = 0; br < 2; ++br) {
        const int causal = (br == 0);
        const unsigned short* __restrict__ qk = causal ? qk_c : qk_ac;
        const unsigned short* __restrict__ vT = causal ? vT_c : vT_ac;
        unsigned short* __restrict__ o = causal ? o_c : o_ac;
        const unsigned short* qbase = qk + (size_t)b * SEQ * QKW + h * HD;
        const unsigned short* kbase = qbase + DIM;
        const unsigned short* vtb   = vT + (size_t)(b * HEADS + h) * HD * SEQ;

        short8 qb0, qb1;
        {
            const size_t qoff = (size_t)(qt * 64 + w * 16 + fm) * QKW + fg * 8;
            qb0 = *(const short8*)(qbase + qoff);
            qb1 = *(const short8*)(qbase + qoff + 32);
        }

        float ls = 0.f;
        f32x4 accO[4];
#pragma unroll
        for (int dj = 0; dj < 4; ++dj) accO[dj] = f32x4{0.f, 0.f, 0.f, 0.f};

        const int ktb = causal ? 0 : qt;
        const int kte = causal ? qt : (SEQ / 64 - 1);

        uint4 kr0 = *(const uint4*)(kbase + (size_t)(ktb * 64 + srow) * QKW + sseg);
        uint4 kr1 = *(const uint4*)(kbase + (size_t)(ktb * 64 + srow + 32) * QKW + sseg);
        uint4 vr0 = *(const uint4*)(vtb + (size_t)srow * SEQ + ktb * 64 + sseg);
        uint4 vr1 = *(const uint4*)(vtb + (size_t)(srow + 32) * SEQ + ktb * 64 + sseg);

        if (br) __syncthreads();
        int p = 0;
        for (int kt = ktb; kt <= kte; ++kt) {
            *(uint4*)(&Kls[p][srow * KP + sseg])        = kr0;
            *(uint4*)(&Kls[p][(srow + 32) * KP + sseg]) = kr1;
            *(uint4*)(&Vls[p][srow * KP + sseg])        = vr0;
            *(uint4*)(&Vls[p][(srow + 32) * KP + sseg]) = vr1;
            if (kt < kte) {
                const int ktn = kt + 1;
                kr0 = *(const uint4*)(kbase + (size_t)(ktn * 64 + srow) * QKW + sseg);
                kr1 = *(const uint4*)(kbase + (size_t)(ktn * 64 + srow + 32) * QKW + sseg);
                vr0 = *(const uint4*)(vtb + (size_t)srow * SEQ + ktn * 64 + sseg);
                vr1 = *(const uint4*)(vtb + (size_t)(srow + 32) * SEQ + ktn * 64 + sseg);
            }
            __syncthreads();

            f32x4 st[4];
#pragma unroll
            for (int kj = 0; kj < 4; ++kj) {
                const short8 ka0 = *(const short8*)&Kls[p][(kj * 16 + fm) * KP + fg * 8];
                const short8 ka1 = *(const short8*)&Kls[p][(kj * 16 + fm) * KP + 32 + fg * 8];
                st[kj] = __builtin_amdgcn_mfma_f32_16x16x32_bf16(ka0, qb0, f32x4{0.f,0.f,0.f,0.f}, 0, 0, 0);
                st[kj] = __builtin_amdgcn_mfma_f32_16x16x32_bf16(ka1, qb1, st[kj], 0, 0, 0);
            }
            const bool diag = (kt == qt);
#pragma unroll
            for (int kj = 0; kj < 4; ++kj) {
                float e[4];
#pragma unroll
                for (int r = 0; r < 4; ++r) {
                    float v = st[kj][r];
                    if (diag) {
                        const int ki = kj * 16 + fg * 4 + r;
                        const int qi = w * 16 + fm;
                        const bool ok = causal ? (ki <= qi) : (ki >= qi);
                        if (!ok) v = -1e30f;
                    }
                    e[r] = __expf(v);
                    ls += e[r];
                }
                const unsigned p0 = f2bf(e[0]);
                const unsigned p1 = f2bf(e[1]);
                const unsigned p2 = f2bf(e[2]);
                const unsigned p3 = f2bf(e[3]);
                uint2 u; u.x = p0 | (p1 << 16); u.y = p2 | (p3 << 16);
                *(uint2*)(Psw + fm * KP + kj * 16 + fg * 4) = u;
            }
            const short8 ap0 = *(const short8*)(Psw + fm * KP + fg * 8);
            const short8 ap1 = *(const short8*)(Psw + fm * KP + 32 + fg * 8);
#pragma unroll
            for (int dj = 0; dj < 4; ++dj) {
                const short8 vb0 = *(const short8*)&Vls[p][(dj * 16 + fm) * KP + fg * 8];
                const short8 vb1 = *(const short8*)&Vls[p][(dj * 16 + fm) * KP + 32 + fg * 8];
                accO[dj] = __builtin_amdgcn_mfma_f32_16x16x32_bf16(ap0, vb0, accO[dj], 0, 0, 0);
                accO[dj] = __builtin_amdgcn_mfma_f32_16x16x32_bf16(ap1, vb1, accO[dj], 0, 0, 0);
            }
            p ^= 1;
        }

        float lt = ls;
        lt += __shfl_xor(lt, 16);
        lt += __shfl_xor(lt, 32);
        float li_o[4];
#pragma unroll
        for (int r = 0; r < 4; ++r) li_o[r] = __shfl(lt, fg * 4 + r);
#pragma unroll
        for (int r = 0; r < 4; ++r) {
            const float inv = 1.f / li_o[r];
            const int q = qt * 64 + w * 16 + fg * 4 + r;
            unsigned short* orow = o + ((size_t)b * SEQ + q) * DIM + h * HD;
#pragma unroll
            for (int dj = 0; dj < 4; ++dj)
                orow[dj * 16 + fm] = f2bf(accO[dj][r] * inv);
        }
    }
}

// ==================== LayerNorm over last dim (768), Y = Y0(f32) + Y1(bf16) ====================
__global__ __launch_bounds__(256) void ln_kernel(
    const float* __restrict__ Y0, const unsigned short* __restrict__ Y1,
    const float* __restrict__ gamma, const float* __restrict__ beta,
    float* __restrict__ out)
{
    const int row = blockIdx.x;
    const int tid = threadIdx.x;
    const float* y0r = Y0 + (size_t)row * DIM;
    const unsigned short* y1r = Y1 + (size_t)row * DIM;
    float v0 = y0r[tid]       + b2f(y1r[tid]);
    float v1 = y0r[tid + 256] + b2f(y1r[tid + 256]);
    float v2 = y0r[tid + 512] + b2f(y1r[tid + 512]);
    float s = v0 + v1 + v2;
    float q = v0 * v0 + v1 * v1 + v2 * v2;
#pragma unroll
    for (int off = 32; off > 0; off >>= 1) {
        s += __shfl_down(s, off);
        q += __shfl_down(q, off);
    }
    __shared__ float rs_[4], rq_[4];
    const int wv = tid >> 6;
    if ((tid & 63) == 0) { rs_[wv] = s; rq_[wv] = q; }
    __syncthreads();
    const float ts = rs_[0] + rs_[1] + rs_[2] + rs_[3];
    const float tq = rq_[0] + rq_[1] + rq_[2] + rq_[3];
    const float mu = ts * (1.f / DIM);
    const float var = tq * (1.f / DIM) - mu * mu;
    const float rstd = rsqrtf(var + EPS);
    out[(size_t)row * DIM + tid]       = (v0 - mu) * rstd * gamma[tid]       + beta[tid];
    out[(size_t)row * DIM + tid + 256] = (v1 - mu) * rstd * gamma[tid + 256] + beta[tid + 256];
    out[(size_t)row * DIM + tid + 512] = (v2 - mu) * rstd * gamma[tid + 512] + beta[tid + 512];
}

// ==================== launch ====================
extern "C" void kernel_launch(void* const* d_in, const int* in_sizes, int n_in,
                              void* d_out, int out_size, void* d_ws, size_t ws_size,
                              hipStream_t stream)
{
    const float* x       = (const float*)d_in[0];
    const float* Wqkv_c  = (const float*)d_in[1];
    const float* bqkv_c  = (const float*)d_in[2];
    const float* Wp_c    = (const float*)d_in[3];
    const float* bp_c    = (const float*)d_in[4];
    const float* Wqkv_ac = (const float*)d_in[5];
    const float* bqkv_ac = (const float*)d_in[6];
    const float* Wp_ac   = (const float*)d_in[7];
    const float* bp_ac   = (const float*)d_in[8];
    const float* gamma   = (const float*)d_in[9];
    const float* beta    = (const float*)d_in[10];
    float* out = (float*)d_out;

    // ws layout, 59.77 MB total:
    char* p = (char*)d_ws;
    unsigned short* qk_c   = (unsigned short*)p; p += (size_t)NTOK * QKW * 2;   // 12.58 MB
    unsigned short* qk_ac  = (unsigned short*)p; p += (size_t)NTOK * QKW * 2;   // 12.58 MB
    unsigned short* vT_c   = (unsigned short*)p; p += (size_t)NTOK * DIM * 2;   // 6.29 MB
    unsigned short* vT_ac  = (unsigned short*)p; p += (size_t)NTOK * DIM * 2;   // 6.29 MB
    unsigned short* o_ac   = (unsigned short*)p; p += (size_t)NTOK * DIM * 2;   // 6.29 MB
    unsigned short* xb     = (unsigned short*)p; p += (size_t)NTOK * DIM * 2;   // 6.29 MB
    unsigned short* WqT_c  = (unsigned short*)p; p += (size_t)QKVW * DIM * 2;   // 3.54 MB
    unsigned short* WqT_ac = (unsigned short*)p; p += (size_t)QKVW * DIM * 2;   // 3.54 MB
    unsigned short* WpT_c  = (unsigned short*)p; p += (size_t)DIM * DIM * 2;    // 1.18 MB
    unsigned short* WpT_ac = (unsigned short*)p; p += (size_t)DIM * DIM * 2;    // 1.18 MB
    // overlays (stream-ordered lifetime, safe):
    unsigned short* o_c = WqT_c;           // attn writes o_c after qkv GEMM's last WqT read
    float*          Y0  = (float*)qk_c;    // proj writes Y0 after attn's last qk read
    unsigned short* Y1  = vT_c;            // proj writes Y1 (bf16) after attn's last vT read

    cvt_all_kernel<<<CVT_X_BLOCKS + 2 * CVT_WQ_TILES + 2 * CVT_WP_TILES, 256, 0, stream>>>(
        x, Wqkv_c, Wqkv_ac, Wp_c, Wp_ac, xb, WqT_c, WqT_ac, WpT_c, WpT_ac);

    // both QKV GEMMs, 1D swizzled grid (XCD-tiled)
    gemm_qkv_kernel<<<(QKVW / 128) * (NTOK / 128) * 2, 256, 0, stream>>>(
        xb, WqT_c, WqT_ac, bqkv_c, bqkv_ac, qk_c, qk_ac, vT_c, vT_ac);

    attn_fused_kernel<<<dim3(BATCH * HEADS, SEQ / 64), 256, 0, stream>>>(
        qk_c, vT_c, qk_ac, vT_ac, o_c, o_ac);

    gemm_proj_kernel<<<dim3(DIM / 128, NTOK / 64, 2), 256, 0, stream>>>(
        o_c, WpT_c, o_ac, WpT_ac, bp_c, bp_ac, x, Y0, Y1);
    ln_kernel<<<NTOK, 256, 0, stream>>>(Y0, Y1, gamma, beta, out);
}

// Round 11
// 194.653 us; speedup vs baseline: 1.0356x; 1.0356x over previous
//
#include <hip/hip_runtime.h>
#include <stdint.h>

#define DIM 768
#define HEADS 12
#define HD 64
#define BATCH 4
#define SEQ 1024
#define NTOK (BATCH*SEQ)   // 4096
#define QKVW (3*DIM)       // 2304
#define QKW (2*DIM)        // 1536
#define EPS 1e-5f

typedef __attribute__((ext_vector_type(8))) short short8;   // 8 bf16 (4 VGPRs)
typedef __attribute__((ext_vector_type(4))) float f32x4;    // MFMA C/D

// ---- fp32 <-> bf16 ----
__device__ __forceinline__ unsigned short f2bf(float f) {
    union { float f; unsigned u; } v; v.f = f;
    unsigned r = v.u + 0x7fffu + ((v.u >> 16) & 1u);   // RNE
    return (unsigned short)(r >> 16);
}
__device__ __forceinline__ float b2f(unsigned short s) {
    union { unsigned u; float f; } v; v.u = (unsigned)s << 16; return v.f;
}

// ---- async global->LDS, 16B per lane ----
__device__ __forceinline__ void gld_lds16(const void* g, void* l) {
    auto gp = reinterpret_cast<const __attribute__((address_space(1))) unsigned int*>(
        (uintptr_t)g);
    auto lp = reinterpret_cast<__attribute__((address_space(3))) unsigned int*>(
        (unsigned int)(uintptr_t)l);
    __builtin_amdgcn_global_load_lds(gp, lp, 16, 0, 0);
}

// ==================== combined conversions (1 launch) ====================
#define CVT_X_BLOCKS (NTOK*DIM/4096)            // 768 (4 float4 per thread)
#define CVT_WQ_TILES ((QKVW/32)*(DIM/32))       // 1728
#define CVT_WP_TILES ((DIM/32)*(DIM/32))        // 576
__global__ __launch_bounds__(256) void cvt_all_kernel(
    const float* __restrict__ x,
    const float* __restrict__ Wq0, const float* __restrict__ Wq1,
    const float* __restrict__ Wp0, const float* __restrict__ Wp1,
    unsigned short* __restrict__ xb,
    unsigned short* __restrict__ WqT0, unsigned short* __restrict__ WqT1,
    unsigned short* __restrict__ WpT0, unsigned short* __restrict__ WpT1)
{
    const int bid = blockIdx.x, tid = threadIdx.x;
    if (bid < CVT_X_BLOCKS) {
        const int base = bid * 1024 + tid;
#pragma unroll
        for (int u = 0; u < 4; ++u) {
            const float4 v = ((const float4*)x)[base + u * 256];
            ushort4 o4;
            o4.x = f2bf(v.x); o4.y = f2bf(v.y); o4.z = f2bf(v.z); o4.w = f2bf(v.w);
            ((ushort4*)xb)[base + u * 256] = o4;
        }
        return;
    }
    __shared__ float t[32][33];
    const float* W; unsigned short* WT; int N, K, tile;
    int w = bid - CVT_X_BLOCKS;
    if (w < 2 * CVT_WQ_TILES) {
        const int z = w / CVT_WQ_TILES; tile = w % CVT_WQ_TILES;
        W = z ? Wq1 : Wq0; WT = z ? WqT1 : WqT0; N = QKVW; K = DIM;
    } else {
        w -= 2 * CVT_WQ_TILES;
        const int z = w / CVT_WP_TILES; tile = w % CVT_WP_TILES;
        W = z ? Wp1 : Wp0; WT = z ? WpT1 : WpT0; N = DIM; K = DIM;
    }
    const int ntiles = N / 32;
    const int n0 = (tile % ntiles) * 32, k0 = (tile / ntiles) * 32;
    const int c = tid & 31, rr = tid >> 5;
#pragma unroll
    for (int i = 0; i < 4; ++i)
        t[rr + 8 * i][c] = W[(size_t)(k0 + rr + 8 * i) * N + n0 + c];
    __syncthreads();
#pragma unroll
    for (int i = 0; i < 4; ++i)
        WT[(size_t)(n0 + rr + 8 * i) * K + k0 + c] = f2bf(t[c][rr + 8 * i]);
}

// ==================== fused QKV GEMM: R9 body (async gld_lds dbuf, 1 barrier)
// + R10 swizzled 1D grid (XCD-tiled: id%8 -> one of 2x2x2 halves of the
// 18x32x2 block space; per-XCD B/A panels stay L2-resident -> FETCH 62->25MB).
__global__ __launch_bounds__(256) void gemm_qkv_kernel(
    const unsigned short* __restrict__ A,     // xb [4096][768]
    const unsigned short* __restrict__ BT0, const unsigned short* __restrict__ BT1,
    const float* __restrict__ bias0, const float* __restrict__ bias1,
    unsigned short* __restrict__ QK0, unsigned short* __restrict__ QK1,
    unsigned short* __restrict__ VT0, unsigned short* __restrict__ VT1)
{
    // swizzled block id decode
    const int gid = blockIdx.x;
    const int g = gid & 7, t = gid >> 3;          // t: 0..143
    const int bx = (g & 1) * 9 + t % 9;           // 0..17
    const int by = ((g >> 1) & 1) * 16 + t / 9;   // 0..31
    const int z = g >> 2;
    const unsigned short* __restrict__ BT = z ? BT1 : BT0;
    const float* __restrict__ bias = z ? bias1 : bias0;
    unsigned short* __restrict__ QK = z ? QK1 : QK0;
    unsigned short* __restrict__ VT = z ? VT1 : VT0;
    const int K = DIM;
    const int m0 = by * 128, n0 = bx * 128;

    // sh: staging buf p at [p*8192] (A 4096 shorts, B 4096 shorts);
    // epilogue reuses sh as C tile [128][136] (17408 shorts)
    __shared__ __align__(16) unsigned short sh[17408];
    const int tid = threadIdx.x, lane = tid & 63, wv = tid >> 6;
    const int wr = wv >> 1, wc = wv & 1;
    const int fm = lane & 15, fk = (lane >> 4) * 8;
    const int c0 = wv * 2;
    const int arow = c0 * 16 + (lane >> 2), kk = (lane & 3) * 8;

    const unsigned short* Ag0 = A  + (size_t)(m0 + arow)      * K + kk;
    const unsigned short* Ag1 = A  + (size_t)(m0 + arow + 16) * K + kk;
    const unsigned short* Bg0 = BT + (size_t)(n0 + arow)      * K + kk;
    const unsigned short* Bg1 = BT + (size_t)(n0 + arow + 16) * K + kk;

    f32x4 acc[4][4];
#pragma unroll
    for (int i = 0; i < 4; ++i)
#pragma unroll
        for (int j = 0; j < 4; ++j) acc[i][j] = f32x4{0.f, 0.f, 0.f, 0.f};

    // prologue: stage tile 0 into buffer 0
    gld_lds16(Ag0, &sh[c0 * 512]);
    gld_lds16(Ag1, &sh[c0 * 512 + 512]);
    gld_lds16(Bg0, &sh[4096 + c0 * 512]);
    gld_lds16(Bg1, &sh[4096 + c0 * 512 + 512]);

    const int NK = K / 32;   // 24
    for (int kt = 0; kt < NK; ++kt) {
        const int p = kt & 1;
        __syncthreads();   // drains buf[p] staging; readers of buf[p^1] done
        if (kt + 1 < NK) {
            const int off = (kt + 1) * 32;
            const int q = (p ^ 1) * 8192;
            gld_lds16(Ag0 + off, &sh[q + c0 * 512]);
            gld_lds16(Ag1 + off, &sh[q + c0 * 512 + 512]);
            gld_lds16(Bg0 + off, &sh[q + 4096 + c0 * 512]);
            gld_lds16(Bg1 + off, &sh[q + 4096 + c0 * 512 + 512]);
        }
        const int pb = p * 8192;
        short8 af[4], bf[4];
#pragma unroll
        for (int i = 0; i < 4; ++i)
            af[i] = *(const short8*)&sh[pb + (wr * 64 + i * 16 + fm) * 32 + fk];
#pragma unroll
        for (int j = 0; j < 4; ++j)
            bf[j] = *(const short8*)&sh[pb + 4096 + (wc * 64 + j * 16 + fm) * 32 + fk];
#pragma unroll
        for (int i = 0; i < 4; ++i)
#pragma unroll
            for (int j = 0; j < 4; ++j)
                acc[i][j] = __builtin_amdgcn_mfma_f32_16x16x32_bf16(af[i], bf[j], acc[i][j], 0, 0, 0);
    }

    __syncthreads();   // all waves done reading the last staged tile; sh free
    const int rbase = (lane >> 4) * 4;
    const int rowg = tid >> 4, lseg = tid & 15;
    if (n0 < QKW) {
        const float qsc = (n0 < DIM) ? 0.125f : 1.0f;   // fold 1/sqrt(64) into Q
#pragma unroll
        for (int i = 0; i < 4; ++i) {
            const int ml = wr * 64 + i * 16 + rbase;
#pragma unroll
            for (int j = 0; j < 4; ++j) {
                const int nl = wc * 64 + j * 16 + fm;
                const float bs = bias[n0 + nl];
#pragma unroll
                for (int r = 0; r < 4; ++r)
                    sh[(ml + r) * 136 + nl] = f2bf((acc[i][j][r] + bs) * qsc);
            }
        }
        __syncthreads();
#pragma unroll
        for (int pp = 0; pp < 8; ++pp) {
            const int row = pp * 16 + rowg;
            const uint4 v = *(const uint4*)&sh[row * 136 + lseg * 8];
            *(uint4*)(QK + (size_t)(m0 + row) * QKW + n0 + lseg * 8) = v;
        }
    } else {
        const int b = m0 >> 10, t0 = m0 & 1023;
#pragma unroll
        for (int i = 0; i < 4; ++i) {
            const int tl = wr * 64 + i * 16 + rbase;
#pragma unroll
            for (int j = 0; j < 4; ++j) {
                const int nl = wc * 64 + j * 16 + fm;
                const float bs = bias[n0 + nl];
                const unsigned p0 = f2bf(acc[i][j][0] + bs);
                const unsigned p1 = f2bf(acc[i][j][1] + bs);
                const unsigned p2 = f2bf(acc[i][j][2] + bs);
                const unsigned p3 = f2bf(acc[i][j][3] + bs);
                uint2 u; u.x = p0 | (p1 << 16); u.y = p2 | (p3 << 16);
                *(uint2*)(&sh[nl * 136 + tl]) = u;
            }
        }
        __syncthreads();
#pragma unroll
        for (int pp = 0; pp < 8; ++pp) {
            const int nl = pp * 16 + rowg;
            const int nh = (n0 - QKW) + nl;
            const uint4 v = *(const uint4*)&sh[nl * 136 + lseg * 8];
            *(uint4*)(VT + ((size_t)((b * HEADS + (nh >> 6)) * HD + (nh & 63))) * SEQ
                      + t0 + lseg * 8) = v;
        }
    }
}

// ==================== proj GEMM (R9 body: async gld_lds dbuf, 1 barrier) ====================
// grid (6, 64, 2): 64x128 tile, K=768 per branch -> 768 blocks (3/CU).
// z=0: Y0 = acc + x + b0 + b1 (fp32); z=1: Y1 = acc (bf16). ln sums Y0+Y1.
__global__ __launch_bounds__(256) void gemm_proj_kernel(
    const unsigned short* __restrict__ A0, const unsigned short* __restrict__ BT0,
    const unsigned short* __restrict__ A1, const unsigned short* __restrict__ BT1,
    const float* __restrict__ b0, const float* __restrict__ b1,
    const float* __restrict__ xres, float* __restrict__ Y0,
    unsigned short* __restrict__ Y1)
{
    const int z = blockIdx.z;
    const unsigned short* __restrict__ A  = z ? A1 : A0;
    const unsigned short* __restrict__ BT = z ? BT1 : BT0;
    __shared__ __align__(16) unsigned short Als[2][64 * 32];    // 2 x 4 KB
    __shared__ __align__(16) unsigned short Bls[2][128 * 32];   // 2 x 8 KB
    const int tid = threadIdx.x, lane = tid & 63, wv = tid >> 6;
    const int m0 = blockIdx.y * 64, n0 = blockIdx.x * 128;
    const int fm = lane & 15, fg = lane >> 4, fk = (lane >> 4) * 8;
    const int srw = lane >> 2, kk = (lane & 3) * 8;
    const int K = DIM;

    const unsigned short* Ag  = A  + (size_t)(m0 + wv * 16 + srw) * K + kk;
    const unsigned short* Bg0 = BT + (size_t)(n0 + wv * 32 + srw) * K + kk;
    const unsigned short* Bg1 = BT + (size_t)(n0 + wv * 32 + 16 + srw) * K + kk;

    f32x4 acc[4][2];
#pragma unroll
    for (int i = 0; i < 4; ++i)
#pragma unroll
        for (int j = 0; j < 2; ++j) acc[i][j] = f32x4{0.f, 0.f, 0.f, 0.f};

    gld_lds16(Ag,  &Als[0][wv * 512]);
    gld_lds16(Bg0, &Bls[0][wv * 1024]);
    gld_lds16(Bg1, &Bls[0][wv * 1024 + 512]);

    const int NK = K / 32;   // 24
    for (int kt = 0; kt < NK; ++kt) {
        const int p = kt & 1;
        __syncthreads();
        if (kt + 1 < NK) {
            const int off = (kt + 1) * 32;
            gld_lds16(Ag + off,  &Als[p ^ 1][wv * 512]);
            gld_lds16(Bg0 + off, &Bls[p ^ 1][wv * 1024]);
            gld_lds16(Bg1 + off, &Bls[p ^ 1][wv * 1024 + 512]);
        }
        short8 af[4], bf[2];
#pragma unroll
        for (int i = 0; i < 4; ++i)
            af[i] = *(const short8*)&Als[p][(i * 16 + fm) * 32 + fk];
#pragma unroll
        for (int j = 0; j < 2; ++j)
            bf[j] = *(const short8*)&Bls[p][(wv * 32 + j * 16 + fm) * 32 + fk];
#pragma unroll
        for (int i = 0; i < 4; ++i)
#pragma unroll
            for (int j = 0; j < 2; ++j)
                acc[i][j] = __builtin_amdgcn_mfma_f32_16x16x32_bf16(af[i], bf[j], acc[i][j], 0, 0, 0);
    }
    // epilogue: C row = fg*4+r (m-dir), col = fm (n-dir)
#pragma unroll
    for (int i = 0; i < 4; ++i) {
        const int m = m0 + i * 16 + fg * 4;
#pragma unroll
        for (int j = 0; j < 2; ++j) {
            const int n = n0 + wv * 32 + j * 16 + fm;
            if (z == 0) {
                const float bs = b0[n] + b1[n];
#pragma unroll
                for (int r = 0; r < 4; ++r) {
                    const size_t idx = (size_t)(m + r) * DIM + n;
                    Y0[idx] = acc[i][j][r] + xres[idx] + bs;
                }
            } else {
#pragma unroll
                for (int r = 0; r < 4; ++r)
                    Y1[(size_t)(m + r) * DIM + n] = f2bf(acc[i][j][r]);
            }
        }
    }
}

// ==================== fused MFMA flash attention, dbuf LDS K/V, 1 barrier/iter ====================
#define KP 72    // LDS pitch in shorts (144B rows)
__global__ __launch_bounds__(256, 3) void attn_fused_kernel(
    const unsigned short* __restrict__ qk_c, const unsigned short* __restrict__ vT_c,
    const unsigned short* __restrict__ qk_ac, const unsigned short* __restrict__ vT_ac,
    unsigned short* __restrict__ o_c, unsigned short* __restrict__ o_ac)
{
    __shared__ __align__(16) unsigned short Kls[2][64 * KP];   // 18 KB
    __shared__ __align__(16) unsigned short Vls[2][64 * KP];   // 18 KB ([d][kc])
    __shared__ __align__(16) unsigned short Ps[4][16 * KP];    // 9 KB, wave-private
    const int tid = threadIdx.x, lane = tid & 63, w = tid >> 6;
    const int fm = lane & 15, fg = lane >> 4;
    const int bh = blockIdx.x, qt = blockIdx.y;
    const int b = bh / HEADS, h = bh % HEADS;
    unsigned short* Psw = &Ps[w][0];
    const int srow = tid >> 3, sseg = (tid & 7) * 8;

    for (int br = 0; br < 2; ++br) {
        const int causal = (br == 0);
        const unsigned short* __restrict__ qk = causal ? qk_c : qk_ac;
        const unsigned short* __restrict__ vT = causal ? vT_c : vT_ac;
        unsigned short* __restrict__ o = causal ? o_c : o_ac;
        const unsigned short* qbase = qk + (size_t)b * SEQ * QKW + h * HD;
        const unsigned short* kbase = qbase + DIM;
        const unsigned short* vtb   = vT + (size_t)(b * HEADS + h) * HD * SEQ;

        short8 qb0, qb1;
        {
            const size_t qoff = (size_t)(qt * 64 + w * 16 + fm) * QKW + fg * 8;
            qb0 = *(const short8*)(qbase + qoff);
            qb1 = *(const short8*)(qbase + qoff + 32);
        }

        float ls = 0.f;
        f32x4 accO[4];
#pragma unroll
        for (int dj = 0; dj < 4; ++dj) accO[dj] = f32x4{0.f, 0.f, 0.f, 0.f};

        const int ktb = causal ? 0 : qt;
        const int kte = causal ? qt : (SEQ / 64 - 1);

        uint4 kr0 = *(const uint4*)(kbase + (size_t)(ktb * 64 + srow) * QKW + sseg);
        uint4 kr1 = *(const uint4*)(kbase + (size_t)(ktb * 64 + srow + 32) * QKW + sseg);
        uint4 vr0 = *(const uint4*)(vtb + (size_t)srow * SEQ + ktb * 64 + sseg);
        uint4 vr1 = *(const uint4*)(vtb + (size_t)(srow + 32) * SEQ + ktb * 64 + sseg);

        if (br) __syncthreads();
        int p = 0;
        for (int kt = ktb; kt <= kte; ++kt) {
            *(uint4*)(&Kls[p][srow * KP + sseg])        = kr0;
            *(uint4*)(&Kls[p][(srow + 32) * KP + sseg]) = kr1;
            *(uint4*)(&Vls[p][srow * KP + sseg])        = vr0;
            *(uint4*)(&Vls[p][(srow + 32) * KP + sseg]) = vr1;
            if (kt < kte) {
                const int ktn = kt + 1;
                kr0 = *(const uint4*)(kbase + (size_t)(ktn * 64 + srow) * QKW + sseg);
                kr1 = *(const uint4*)(kbase + (size_t)(ktn * 64 + srow + 32) * QKW + sseg);
                vr0 = *(const uint4*)(vtb + (size_t)srow * SEQ + ktn * 64 + sseg);
                vr1 = *(const uint4*)(vtb + (size_t)(srow + 32) * SEQ + ktn * 64 + sseg);
            }
            __syncthreads();

            f32x4 st[4];
#pragma unroll
            for (int kj = 0; kj < 4; ++kj) {
                const short8 ka0 = *(const short8*)&Kls[p][(kj * 16 + fm) * KP + fg * 8];
                const short8 ka1 = *(const short8*)&Kls[p][(kj * 16 + fm) * KP + 32 + fg * 8];
                st[kj] = __builtin_amdgcn_mfma_f32_16x16x32_bf16(ka0, qb0, f32x4{0.f,0.f,0.f,0.f}, 0, 0, 0);
                st[kj] = __builtin_amdgcn_mfma_f32_16x16x32_bf16(ka1, qb1, st[kj], 0, 0, 0);
            }
            const bool diag = (kt == qt);
#pragma unroll
            for (int kj = 0; kj < 4; ++kj) {
                float e[4];
#pragma unroll
                for (int r = 0; r < 4; ++r) {
                    float v = st[kj][r];
                    if (diag) {
                        const int ki = kj * 16 + fg * 4 + r;
                        const int qi = w * 16 + fm;
                        const bool ok = causal ? (ki <= qi) : (ki >= qi);
                        if (!ok) v = -1e30f;
                    }
                    e[r] = __expf(v);
                    ls += e[r];
                }
                // cheap truncate-pack (P >= 0, <=2^-8 one-sided rel err; denom fp32)
                union { float f; unsigned u; } u0, u1, u2, u3;
                u0.f = e[0]; u1.f = e[1]; u2.f = e[2]; u3.f = e[3];
                uint2 u;
                u.x = (u0.u >> 16) | (u1.u & 0xffff0000u);
                u.y = (u2.u >> 16) | (u3.u & 0xffff0000u);
                *(uint2*)(Psw + fm * KP + kj * 16 + fg * 4) = u;
            }
            const short8 ap0 = *(const short8*)(Psw + fm * KP + fg * 8);
            const short8 ap1 = *(const short8*)(Psw + fm * KP + 32 + fg * 8);
#pragma unroll
            for (int dj = 0; dj < 4; ++dj) {
                const short8 vb0 = *(const short8*)&Vls[p][(dj * 16 + fm) * KP + fg * 8];
                const short8 vb1 = *(const short8*)&Vls[p][(dj * 16 + fm) * KP + 32 + fg * 8];
                accO[dj] = __builtin_amdgcn_mfma_f32_16x16x32_bf16(ap0, vb0, accO[dj], 0, 0, 0);
                accO[dj] = __builtin_amdgcn_mfma_f32_16x16x32_bf16(ap1, vb1, accO[dj], 0, 0, 0);
            }
            p ^= 1;
        }

        float lt = ls;
        lt += __shfl_xor(lt, 16);
        lt += __shfl_xor(lt, 32);
        float li_o[4];
#pragma unroll
        for (int r = 0; r < 4; ++r) li_o[r] = __shfl(lt, fg * 4 + r);
#pragma unroll
        for (int r = 0; r < 4; ++r) {
            const float inv = 1.f / li_o[r];
            const int q = qt * 64 + w * 16 + fg * 4 + r;
            unsigned short* orow = o + ((size_t)b * SEQ + q) * DIM + h * HD;
#pragma unroll
            for (int dj = 0; dj < 4; ++dj)
                orow[dj * 16 + fm] = f2bf(accO[dj][r] * inv);
        }
    }
}

// ==================== LayerNorm over last dim (768), Y = Y0(f32) + Y1(bf16) ====================
__global__ __launch_bounds__(256) void ln_kernel(
    const float* __restrict__ Y0, const unsigned short* __restrict__ Y1,
    const float* __restrict__ gamma, const float* __restrict__ beta,
    float* __restrict__ out)
{
    const int row = blockIdx.x;
    const int tid = threadIdx.x;
    const float* y0r = Y0 + (size_t)row * DIM;
    const unsigned short* y1r = Y1 + (size_t)row * DIM;
    float v0 = y0r[tid]       + b2f(y1r[tid]);
    float v1 = y0r[tid + 256] + b2f(y1r[tid + 256]);
    float v2 = y0r[tid + 512] + b2f(y1r[tid + 512]);
    float s = v0 + v1 + v2;
    float q = v0 * v0 + v1 * v1 + v2 * v2;
#pragma unroll
    for (int off = 32; off > 0; off >>= 1) {
        s += __shfl_down(s, off);
        q += __shfl_down(q, off);
    }
    __shared__ float rs_[4], rq_[4];
    const int wv = tid >> 6;
    if ((tid & 63) == 0) { rs_[wv] = s; rq_[wv] = q; }
    __syncthreads();
    const float ts = rs_[0] + rs_[1] + rs_[2] + rs_[3];
    const float tq = rq_[0] + rq_[1] + rq_[2] + rq_[3];
    const float mu = ts * (1.f / DIM);
    const float var = tq * (1.f / DIM) - mu * mu;
    const float rstd = rsqrtf(var + EPS);
    out[(size_t)row * DIM + tid]       = (v0 - mu) * rstd * gamma[tid]       + beta[tid];
    out[(size_t)row * DIM + tid + 256] = (v1 - mu) * rstd * gamma[tid + 256] + beta[tid + 256];
    out[(size_t)row * DIM + tid + 512] = (v2 - mu) * rstd * gamma[tid + 512] + beta[tid + 512];
}

// ==================== launch ====================
extern "C" void kernel_launch(void* const* d_in, const int* in_sizes, int n_in,
                              void* d_out, int out_size, void* d_ws, size_t ws_size,
                              hipStream_t stream)
{
    const float* x       = (const float*)d_in[0];
    const float* Wqkv_c  = (const float*)d_in[1];
    const float* bqkv_c  = (const float*)d_in[2];
    const float* Wp_c    = (const float*)d_in[3];
    const float* bp_c    = (const float*)d_in[4];
    const float* Wqkv_ac = (const float*)d_in[5];
    const float* bqkv_ac = (const float*)d_in[6];
    const float* Wp_ac   = (const float*)d_in[7];
    const float* bp_ac   = (const float*)d_in[8];
    const float* gamma   = (const float*)d_in[9];
    const float* beta    = (const float*)d_in[10];
    float* out = (float*)d_out;

    // ws layout, 59.77 MB total:
    char* p = (char*)d_ws;
    unsigned short* qk_c   = (unsigned short*)p; p += (size_t)NTOK * QKW * 2;   // 12.58 MB
    unsigned short* qk_ac  = (unsigned short*)p; p += (size_t)NTOK * QKW * 2;   // 12.58 MB
    unsigned short* vT_c   = (unsigned short*)p; p += (size_t)NTOK * DIM * 2;   // 6.29 MB
    unsigned short* vT_ac  = (unsigned short*)p; p += (size_t)NTOK * DIM * 2;   // 6.29 MB
    unsigned short* o_ac   = (unsigned short*)p; p += (size_t)NTOK * DIM * 2;   // 6.29 MB
    unsigned short* xb     = (unsigned short*)p; p += (size_t)NTOK * DIM * 2;   // 6.29 MB
    unsigned short* WqT_c  = (unsigned short*)p; p += (size_t)QKVW * DIM * 2;   // 3.54 MB
    unsigned short* WqT_ac = (unsigned short*)p; p += (size_t)QKVW * DIM * 2;   // 3.54 MB
    unsigned short* WpT_c  = (unsigned short*)p; p += (size_t)DIM * DIM * 2;    // 1.18 MB
    unsigned short* WpT_ac = (unsigned short*)p; p += (size_t)DIM * DIM * 2;    // 1.18 MB
    // overlays (stream-ordered lifetime, safe):
    unsigned short* o_c = WqT_c;           // attn writes o_c after qkv GEMM's last WqT read
    float*          Y0  = (float*)qk_c;    // proj writes Y0 after attn's last qk read
    unsigned short* Y1  = vT_c;            // proj writes Y1 (bf16) after attn's last vT read

    cvt_all_kernel<<<CVT_X_BLOCKS + 2 * CVT_WQ_TILES + 2 * CVT_WP_TILES, 256, 0, stream>>>(
        x, Wqkv_c, Wqkv_ac, Wp_c, Wp_ac, xb, WqT_c, WqT_ac, WpT_c, WpT_ac);

    // both QKV GEMMs, 1D swizzled grid (XCD-tiled), R9 staging structure
    gemm_qkv_kernel<<<(QKVW / 128) * (NTOK / 128) * 2, 256, 0, stream>>>(
        xb, WqT_c, WqT_ac, bqkv_c, bqkv_ac, qk_c, qk_ac, vT_c, vT_ac);

    attn_fused_kernel<<<dim3(BATCH * HEADS, SEQ / 64), 256, 0, stream>>>(
        qk_c, vT_c, qk_ac, vT_ac, o_c, o_ac);

    gemm_proj_kernel<<<dim3(DIM / 128, NTOK / 64, 2), 256, 0, stream>>>(
        o_c, WpT_c, o_ac, WpT_ac, bp_c, bp_ac, x, Y0, Y1);
    ln_kernel<<<NTOK, 256, 0, stream>>>(Y0, Y1, gamma, beta, out);
}